// Round 1
// baseline (638.316 us; speedup 1.0000x reference)
//
#include <hip/hip_runtime.h>
#include <math.h>

#define TT 8
#define NN 10000
#define EE 32768
#define CC 40
#define EPSV 1e-05f

// 1/sqrt(3), 1/sqrt(6), 1/sqrt(20), 1/sqrt(20), 1/sqrt(4)
constexpr float INV3 = 0.57735026918962576f;
constexpr float INV6 = 0.40824829046386302f;
constexpr float N0F  = 0.22360679774997896f;
constexpr float N1OF = 0.22360679774997896f;
constexpr float N1EF = 0.5f;

// cos/sin(pi*t/4) for t=0..7 (irfft basis for mode 1)
constexpr float CTab[8] = {1.f, 0.70710678118654752f, 0.f, -0.70710678118654752f,
                           -1.f, -0.70710678118654752f, 0.f, 0.70710678118654752f};
constexpr float STab[8] = {0.f, 0.70710678118654752f, 1.f, 0.70710678118654752f,
                           0.f, -0.70710678118654752f, -1.f, -0.70710678118654752f};

__device__ __forceinline__ void atomAdd(float* p, float v) {
  __hip_atomic_fetch_add(p, v, __ATOMIC_RELAXED, __HIP_MEMORY_SCOPE_AGENT);
}

// ---------------- transpose w_mlp2 (48,416) -> W2T (416,48) ----------------
__global__ __launch_bounds__(256) void k_tr(const float* __restrict__ W2,
                                            float* __restrict__ W2T) {
  int idx = blockIdx.x * 256 + threadIdx.x;
  if (idx >= 416 * 48) return;
  int k = idx / 48, j = idx - k * 48;
  W2T[idx] = W2[j * 416 + k];
}

// ---------------- spectral conv: x_scalar (T,N,16) ----------------
// Only modes 0,1 survive. irfft drops Im of bin 0:
//   xsc[t,n,o] = (1/8) * ( ReF0 + 2*(ReF1*cos(pi t/4) - ImF1*sin(pi t/4)) )
__global__ __launch_bounds__(256) void k_spec(const float* __restrict__ x,
                                              const float* __restrict__ wr,
                                              const float* __restrict__ wi,
                                              float* __restrict__ xsc) {
  int n = blockIdx.x * 256 + threadIdx.x;
  if (n >= NN) return;
  float F0[16], A[16], B[16];
#pragma unroll
  for (int i = 0; i < 16; ++i) { F0[i] = 0.f; A[i] = 0.f; B[i] = 0.f; }
#pragma unroll
  for (int t = 0; t < 8; ++t) {
    const float* xp = x + ((size_t)t * NN + n) * 28;
    const float ct = CTab[t], st = STab[t];
#pragma unroll
    for (int i = 0; i < 16; ++i) {
      float v = xp[i];
      F0[i] += v;
      A[i] = fmaf(v, ct, A[i]);
      B[i] = fmaf(v, -st, B[i]);  // xf1 = A + iB, B = -sum x*sin
    }
  }
  for (int o = 0; o < 16; ++o) {  // uniform loop
    float r0 = 0.f, r1 = 0.f, i1 = 0.f;
#pragma unroll
    for (int i = 0; i < 16; ++i) {
      // tc_w* layout (16,16,2): [i][o][m] -> i*32 + o*2 + m
      float wr0 = wr[i * 32 + o * 2 + 0];
      float wr1 = wr[i * 32 + o * 2 + 1];
      float wi1 = wi[i * 32 + o * 2 + 1];
      r0 = fmaf(F0[i], wr0, r0);
      r1 += A[i] * wr1 - B[i] * wi1;
      i1 += A[i] * wi1 + B[i] * wr1;
    }
#pragma unroll
    for (int t = 0; t < 8; ++t) {
      float val = 0.125f * (r0 + 2.f * (r1 * CTab[t] - i1 * STab[t]));
      xsc[((size_t)t * NN + n) * 16 + o] = val;
    }
  }
}

// ---------------- edge counts ----------------
__global__ __launch_bounds__(256) void k_cnt(const int* __restrict__ ei,
                                             float* __restrict__ cnt) {
  int e = blockIdx.x * 256 + threadIdx.x;
  if (e >= EE) return;
  atomAdd(cnt + ei[EE + e], 1.f);
}

// ---------------- fused MLP1 + MLP2 + tensor product + scatter ----------------
__global__ __launch_bounds__(256) void k_edge(
    const float* __restrict__ x,     // (T,N,28)
    const int* __restrict__ ei,      // (2,E)
    const float* __restrict__ eag,   // (T,E,48)
    const float* __restrict__ shg,   // (T,E,4)
    const float* __restrict__ W1,    // (48,48) [i][j]
    const float* __restrict__ b1,    // (48)
    const float* __restrict__ W2T,   // (416,48) [k][j]
    const float* __restrict__ b2,    // (416)
    float* __restrict__ seg)         // (T,N,40)
{
  int gid = blockIdx.x * 256 + threadIdx.x;
  int e = gid & (EE - 1);
  int t = gid >> 15;
  int src = ei[e];
  int dst = ei[EE + e];

  // ---- MLP1: h = relu(ea @ W1 + b1), h kept in registers (static indices) ----
  float h[48];
#pragma unroll
  for (int j = 0; j < 48; ++j) h[j] = b1[j];
  const float4* ea4 = (const float4*)(eag + ((size_t)t * EE + e) * 48);
  for (int i4 = 0; i4 < 12; ++i4) {  // uniform loop, small code
    float4 v = ea4[i4];
    const float* w0 = W1 + (4 * i4 + 0) * 48;
    const float* w1 = W1 + (4 * i4 + 1) * 48;
    const float* w2 = W1 + (4 * i4 + 2) * 48;
    const float* w3 = W1 + (4 * i4 + 3) * 48;
#pragma unroll
    for (int j = 0; j < 48; ++j) {
      float a = fmaf(v.x, w0[j], h[j]);
      a = fmaf(v.y, w1[j], a);
      a = fmaf(v.z, w2[j], a);
      h[j] = fmaf(v.w, w3[j], a);
    }
  }
#pragma unroll
  for (int j = 0; j < 48; ++j) h[j] = fmaxf(h[j], 0.f);

  // ---- gather node features ----
  const float* xr = x + ((size_t)t * NN + src) * 28;
  float s_[16];
#pragma unroll
  for (int i = 0; i < 16; ++i) s_[i] = xr[i];
  float v_[4][3];
#pragma unroll
  for (int i = 0; i < 4; ++i)
#pragma unroll
    for (int d = 0; d < 3; ++d) v_[i][d] = xr[16 + 3 * i + d];
  const float* shp = shg + ((size_t)t * EE + e) * 4;
  float sh0 = shp[0], sh1x = shp[1], sh1y = shp[2], sh1z = shp[3];

  float vd[4], cr[4][3];
#pragma unroll
  for (int i = 0; i < 4; ++i) {
    vd[i] = (v_[i][0] * sh1x + v_[i][1] * sh1y + v_[i][2] * sh1z) * INV3;
    cr[i][0] = (v_[i][1] * sh1z - v_[i][2] * sh1y) * INV6;
    cr[i][1] = (v_[i][2] * sh1x - v_[i][0] * sh1z) * INV6;
    cr[i][2] = (v_[i][0] * sh1y - v_[i][1] * sh1x) * INV6;
  }

  float* segp = seg + ((size_t)t * NN + dst) * 40;

  // ---- out0[o] = n0*( sh0*sum_i s_i*ew[16i+o] + sum_i vd_i*ew[336+16i+o] ) ----
  for (int o = 0; o < 16; ++o) {  // uniform
    float acc = 0.f;
#pragma unroll
    for (int i = 0; i < 16; ++i) {
      int k = 16 * i + o;
      const float* w = W2T + k * 48;
      float ewk = b2[k];
#pragma unroll
      for (int j = 0; j < 48; ++j) ewk = fmaf(h[j], w[j], ewk);
      acc = fmaf(s_[i] * sh0, ewk, acc);
    }
#pragma unroll
    for (int i = 0; i < 4; ++i) {
      int k = 336 + 16 * i + o;
      const float* w = W2T + k * 48;
      float ewk = b2[k];
#pragma unroll
      for (int j = 0; j < 48; ++j) ewk = fmaf(h[j], w[j], ewk);
      acc = fmaf(vd[i], ewk, acc);
    }
    atomAdd(segp + o, acc * N0F);
  }

  // ---- out1o[o,d], out1e[o,d], o=0..3 ----
  for (int o = 0; o < 4; ++o) {  // uniform
    float pre2 = 0.f;
#pragma unroll
    for (int i = 0; i < 16; ++i) {
      int k = 256 + 4 * i + o;
      const float* w = W2T + k * 48;
      float ewk = b2[k];
#pragma unroll
      for (int j = 0; j < 48; ++j) ewk = fmaf(h[j], w[j], ewk);
      pre2 = fmaf(s_[i], ewk, pre2);
    }
    float p3x = 0.f, p3y = 0.f, p3z = 0.f;
#pragma unroll
    for (int i = 0; i < 4; ++i) {
      int k = 320 + 4 * i + o;
      const float* w = W2T + k * 48;
      float ewk = b2[k];
#pragma unroll
      for (int j = 0; j < 48; ++j) ewk = fmaf(h[j], w[j], ewk);
      p3x = fmaf(v_[i][0], ewk, p3x);
      p3y = fmaf(v_[i][1], ewk, p3y);
      p3z = fmaf(v_[i][2], ewk, p3z);
    }
    const float f = INV3 * N1OF;
    atomAdd(segp + 16 + 3 * o + 0, (sh1x * pre2 + sh0 * p3x) * f);
    atomAdd(segp + 16 + 3 * o + 1, (sh1y * pre2 + sh0 * p3y) * f);
    atomAdd(segp + 16 + 3 * o + 2, (sh1z * pre2 + sh0 * p3z) * f);

    float e1x = 0.f, e1y = 0.f, e1z = 0.f;
#pragma unroll
    for (int i = 0; i < 4; ++i) {
      int k = 400 + 4 * i + o;
      const float* w = W2T + k * 48;
      float ewk = b2[k];
#pragma unroll
      for (int j = 0; j < 48; ++j) ewk = fmaf(h[j], w[j], ewk);
      e1x = fmaf(cr[i][0], ewk, e1x);
      e1y = fmaf(cr[i][1], ewk, e1y);
      e1z = fmaf(cr[i][2], ewk, e1z);
    }
    atomAdd(segp + 28 + 3 * o + 0, e1x * N1EF);
    atomAdd(segp + 28 + 3 * o + 1, e1y * N1EF);
    atomAdd(segp + 28 + 3 * o + 2, e1z * N1EF);
  }
}

// ---------------- y = seg/max(cnt,1) (+xsc on c<16), in-place; BN stats ----------------
// stats column j = 8*(c%5) + t ; block handles fixed t, 256 nodes
__global__ __launch_bounds__(256) void k_stats(float* __restrict__ seg,
                                               const float* __restrict__ cnt,
                                               const float* __restrict__ xsc,
                                               float* __restrict__ stats) {
  int b = blockIdx.x;          // 0..319
  int t = b / 40;
  int chunk = b - t * 40;
  int n = chunk * 256 + threadIdx.x;
  float p[5] = {0.f, 0.f, 0.f, 0.f, 0.f};
  float q[5] = {0.f, 0.f, 0.f, 0.f, 0.f};
  if (n < NN) {
    float rc = 1.f / fmaxf(cnt[n], 1.f);
    float* sp = seg + ((size_t)t * NN + n) * 40;
    const float* xp = xsc + ((size_t)t * NN + n) * 16;
#pragma unroll
    for (int c = 0; c < 40; ++c) {
      float y = sp[c] * rc + (c < 16 ? xp[c] : 0.f);
      sp[c] = y;
      p[c % 5] += y;
      q[c % 5] = fmaf(y, y, q[c % 5]);
    }
  }
  // wave butterfly reduce
#pragma unroll
  for (int r = 0; r < 5; ++r) {
#pragma unroll
    for (int m = 32; m >= 1; m >>= 1) {
      p[r] += __shfl_xor(p[r], m);
      q[r] += __shfl_xor(q[r], m);
    }
  }
  __shared__ float ls[4][10];
  int lane = threadIdx.x & 63, wv = threadIdx.x >> 6;
  if (lane == 0) {
#pragma unroll
    for (int r = 0; r < 5; ++r) { ls[wv][r] = p[r]; ls[wv][5 + r] = q[r]; }
  }
  __syncthreads();
  if (threadIdx.x < 10) {
    int tid = threadIdx.x;
    float sum = ls[0][tid] + ls[1][tid] + ls[2][tid] + ls[3][tid];
    int r = tid % 5;
    int j = 8 * r + t;
    atomAdd(stats + (tid >= 5 ? 40 + j : j), sum);
  }
}

// ---------------- normalize ----------------
__global__ __launch_bounds__(256) void k_norm(const float* __restrict__ seg,
                                              const float* __restrict__ stats,
                                              const float* __restrict__ gam,
                                              const float* __restrict__ bet,
                                              float* __restrict__ out) {
  int idx = blockIdx.x * 256 + threadIdx.x;
  if (idx >= TT * NN * CC) return;
  int c = idx % 40;
  int t = idx / (NN * CC);
  int j = 8 * (c % 5) + t;
  const float inv = 1.f / (8.f * (float)NN);
  float mu = stats[j] * inv;
  float var = stats[40 + j] * inv - mu * mu;
  float y = seg[idx];
  out[idx] = (y - mu) * rsqrtf(var + EPSV) * gam[j] + bet[j];
}

extern "C" void kernel_launch(void* const* d_in, const int* in_sizes, int n_in,
                              void* d_out, int out_size, void* d_ws, size_t ws_size,
                              hipStream_t stream) {
  const float* x   = (const float*)d_in[0];
  const int*   ei  = (const int*)d_in[1];
  const float* ea  = (const float*)d_in[2];
  const float* esh = (const float*)d_in[3];
  const float* W1  = (const float*)d_in[4];
  const float* b1  = (const float*)d_in[5];
  const float* W2  = (const float*)d_in[6];
  const float* b2  = (const float*)d_in[7];
  const float* wr  = (const float*)d_in[8];
  const float* wi  = (const float*)d_in[9];
  const float* gam = (const float*)d_in[10];
  const float* bet = (const float*)d_in[11];
  float* out = (float*)d_out;

  float* ws    = (float*)d_ws;
  float* seg   = ws;                            // T*N*40 = 3,200,000
  float* cnt   = seg + (size_t)TT * NN * CC;    // 10,000
  float* stats = cnt + NN;                      // 80
  float* xsc   = stats + 80;                    // T*N*16 = 1,280,000
  float* W2T   = xsc + (size_t)TT * NN * 16;    // 416*48 = 19,968

  // zero seg + cnt + stats (contiguous)
  hipMemsetAsync(seg, 0, ((size_t)TT * NN * CC + NN + 80) * sizeof(float), stream);

  k_tr<<<(416 * 48 + 255) / 256, 256, 0, stream>>>(W2, W2T);
  k_spec<<<(NN + 255) / 256, 256, 0, stream>>>(x, wr, wi, xsc);
  k_cnt<<<EE / 256, 256, 0, stream>>>(ei, cnt);
  k_edge<<<TT * EE / 256, 256, 0, stream>>>(x, ei, ea, esh, W1, b1, W2T, b2, seg);
  k_stats<<<8 * 40, 256, 0, stream>>>(seg, cnt, xsc, stats);
  k_norm<<<(TT * NN * CC + 255) / 256, 256, 0, stream>>>(seg, stats, gam, bet, out);
}

// Round 2
// 226.240 us; speedup vs baseline: 2.8214x; 2.8214x over previous
//
#include <hip/hip_runtime.h>
#include <math.h>

#define TT 8
#define NN 10000
#define EE 32768
#define CC 40
#define EPSV 1e-05f

constexpr float INV3 = 0.57735026918962576f;
constexpr float INV6 = 0.40824829046386302f;
constexpr float N0F  = 0.22360679774997896f;
constexpr float N1OF = 0.22360679774997896f;
constexpr float N1EF = 0.5f;

constexpr float CTab[8] = {1.f, 0.70710678118654752f, 0.f, -0.70710678118654752f,
                           -1.f, -0.70710678118654752f, 0.f, 0.70710678118654752f};
constexpr float STab[8] = {0.f, 0.70710678118654752f, 1.f, 0.70710678118654752f,
                           0.f, -0.70710678118654752f, -1.f, -0.70710678118654752f};

typedef __attribute__((ext_vector_type(8))) short short8;
typedef __attribute__((ext_vector_type(4))) float f32x4;

__device__ __forceinline__ void atomAdd(float* p, float v) {
  __hip_atomic_fetch_add(p, v, __ATOMIC_RELAXED, __HIP_MEMORY_SCOPE_AGENT);
}

// fp32 -> bf16 bits (RNE)
__device__ __forceinline__ short f2bfs(float f) {
  unsigned u = __builtin_bit_cast(unsigned, f);
  u = (u + 0x7fffu + ((u >> 16) & 1u)) >> 16;
  return (short)u;
}

// ---------------- pack W1 (48x48) and W2 (48x416) into MFMA B-fragment order, bf16 ----
// layout: [tile][kt][lane][elem] ; value = W[j, n],
//   j = kt*32 + (lane>>4)*4 + (elem&3) + 16*(elem>>2)   (j>=48 -> 0 pad)
//   n = tile*16 + (lane&15)
__global__ __launch_bounds__(256) void k_prep(const float* __restrict__ W1,
                                              const float* __restrict__ W2,
                                              short* __restrict__ W1F,
                                              short* __restrict__ W2F) {
  int idx = blockIdx.x * 256 + threadIdx.x;
  const int tot1 = 3 * 2 * 64 * 8;
  const int tot2 = 26 * 2 * 64 * 8;
  if (idx < tot1) {
    int elem = idx & 7, lane = (idx >> 3) & 63, kt = (idx >> 9) & 1, nt = idx >> 10;
    int j = kt * 32 + ((lane >> 4) << 2) + (elem & 3) + ((elem >> 2) << 4);
    int n = nt * 16 + (lane & 15);
    W1F[idx] = (j < 48) ? f2bfs(W1[j * 48 + n]) : (short)0;
  } else if (idx < tot1 + tot2) {
    int id2 = idx - tot1;
    int elem = id2 & 7, lane = (id2 >> 3) & 63, kt = (id2 >> 9) & 1, ck = id2 >> 10;
    int j = kt * 32 + ((lane >> 4) << 2) + (elem & 3) + ((elem >> 2) << 4);
    int n = ck * 16 + (lane & 15);
    W2F[id2] = (j < 48) ? f2bfs(W2[j * 416 + n]) : (short)0;
  }
}

// ---------------- spectral conv (unchanged) ----------------
__global__ __launch_bounds__(256) void k_spec(const float* __restrict__ x,
                                              const float* __restrict__ wr,
                                              const float* __restrict__ wi,
                                              float* __restrict__ xsc) {
  int n = blockIdx.x * 256 + threadIdx.x;
  if (n >= NN) return;
  float F0[16], A[16], B[16];
#pragma unroll
  for (int i = 0; i < 16; ++i) { F0[i] = 0.f; A[i] = 0.f; B[i] = 0.f; }
#pragma unroll
  for (int t = 0; t < 8; ++t) {
    const float* xp = x + ((size_t)t * NN + n) * 28;
    const float ct = CTab[t], st = STab[t];
#pragma unroll
    for (int i = 0; i < 16; ++i) {
      float v = xp[i];
      F0[i] += v;
      A[i] = fmaf(v, ct, A[i]);
      B[i] = fmaf(v, -st, B[i]);
    }
  }
  for (int o = 0; o < 16; ++o) {
    float r0 = 0.f, r1 = 0.f, i1 = 0.f;
#pragma unroll
    for (int i = 0; i < 16; ++i) {
      float wr0 = wr[i * 32 + o * 2 + 0];
      float wr1 = wr[i * 32 + o * 2 + 1];
      float wi1 = wi[i * 32 + o * 2 + 1];
      r0 = fmaf(F0[i], wr0, r0);
      r1 += A[i] * wr1 - B[i] * wi1;
      i1 += A[i] * wi1 + B[i] * wr1;
    }
#pragma unroll
    for (int t = 0; t < 8; ++t) {
      float val = 0.125f * (r0 + 2.f * (r1 * CTab[t] - i1 * STab[t]));
      xsc[((size_t)t * NN + n) * 16 + o] = val;
    }
  }
}

__global__ __launch_bounds__(256) void k_cnt(const int* __restrict__ ei,
                                             float* __restrict__ cnt) {
  int e = blockIdx.x * 256 + threadIdx.x;
  if (e >= EE) return;
  atomAdd(cnt + ei[EE + e], 1.f);
}

// ---------------- fused MFMA edge kernel ----------------
// block = 256 thr = 4 waves; wave handles 16 edges; block = 64 edges of one t.
__global__ __launch_bounds__(256) void k_edge2(
    const float* __restrict__ x,     // (T,N,28)
    const int* __restrict__ ei,      // (2,E)
    const float* __restrict__ eag,   // (T,E,48)
    const float* __restrict__ shg,   // (T,E,4)
    const short* __restrict__ W1F,   // packed frags
    const short* __restrict__ W2F,
    const float* __restrict__ b1,
    const float* __restrict__ b2,
    float* __restrict__ seg)         // (T,N,40)
{
  __shared__ float cSs[16][64];   // s_i*sh0*N0F
  __shared__ float rawSs[16][64]; // s_i
  __shared__ float cVDs[4][64];   // vd_i*N0F
  __shared__ float vS0s[12][64];  // v_i[d]*sh0*INV3*N1OF
  __shared__ float sh1fs[3][64];  // sh1[d]*INV3*N1OF
  __shared__ float cCRs[12][64];  // cross(v_i,sh1)[d]*INV6*N1EF
  __shared__ int   dsts[64];
  __shared__ ushort Hs[4][16][64]; // per-wave H tile, XOR-swizzled cols

  int blk = blockIdx.x;
  int t = blk >> 9;
  int e0 = (blk & 511) * 64;
  int tid = threadIdx.x;

  // ---- per-edge feature staging (64 threads) ----
  if (tid < 64) {
    int e = e0 + tid;
    int src = ei[e];
    dsts[tid] = ei[EE + e];
    const float* xr = x + ((size_t)t * NN + src) * 28;
    const float* shp = shg + ((size_t)t * EE + e) * 4;
    float sh0 = shp[0], s1x = shp[1], s1y = shp[2], s1z = shp[3];
    const float F1 = INV3 * N1OF;
    sh1fs[0][tid] = s1x * F1; sh1fs[1][tid] = s1y * F1; sh1fs[2][tid] = s1z * F1;
#pragma unroll
    for (int i = 0; i < 16; ++i) {
      float s = xr[i];
      rawSs[i][tid] = s;
      cSs[i][tid] = s * sh0 * N0F;
    }
#pragma unroll
    for (int i = 0; i < 4; ++i) {
      float vx = xr[16 + 3 * i], vy = xr[17 + 3 * i], vz = xr[18 + 3 * i];
      cVDs[i][tid] = (vx * s1x + vy * s1y + vz * s1z) * INV3 * N0F;
      vS0s[3 * i + 0][tid] = vx * sh0 * F1;
      vS0s[3 * i + 1][tid] = vy * sh0 * F1;
      vS0s[3 * i + 2][tid] = vz * sh0 * F1;
      cCRs[3 * i + 0][tid] = (vy * s1z - vz * s1y) * INV6 * N1EF;
      cCRs[3 * i + 1][tid] = (vz * s1x - vx * s1z) * INV6 * N1EF;
      cCRs[3 * i + 2][tid] = (vx * s1y - vy * s1x) * INV6 * N1EF;
    }
  }
  __syncthreads();

  int w = tid >> 6, l = tid & 63;
  int col = l & 15;           // C col / A row / B col
  int kq  = (l >> 4) << 2;    // 0,4,8,12
  int eb  = w * 16;

  // ---- GEMM1: H = relu(EA @ W1 + b1) ----
  const float* row = eag + ((size_t)t * EE + e0 + eb + col) * 48;
  float4 fa = *(const float4*)(row + kq);
  float4 fb = *(const float4*)(row + 16 + kq);
  float4 fc = *(const float4*)(row + 32 + kq);
  short8 a0, a1;
  a0[0] = f2bfs(fa.x); a0[1] = f2bfs(fa.y); a0[2] = f2bfs(fa.z); a0[3] = f2bfs(fa.w);
  a0[4] = f2bfs(fb.x); a0[5] = f2bfs(fb.y); a0[6] = f2bfs(fb.z); a0[7] = f2bfs(fb.w);
  a1[0] = f2bfs(fc.x); a1[1] = f2bfs(fc.y); a1[2] = f2bfs(fc.z); a1[3] = f2bfs(fc.w);
  a1[4] = 0; a1[5] = 0; a1[6] = 0; a1[7] = 0;

  const short8* w1f = (const short8*)W1F;
  const short8* w2f = (const short8*)W2F;

#pragma unroll
  for (int nt = 0; nt < 3; ++nt) {
    float bias = b1[nt * 16 + col];
    f32x4 c = {bias, bias, bias, bias};
    c = __builtin_amdgcn_mfma_f32_16x16x32_bf16(a0, w1f[(nt * 2 + 0) * 64 + l], c, 0, 0, 0);
    c = __builtin_amdgcn_mfma_f32_16x16x32_bf16(a1, w1f[(nt * 2 + 1) * 64 + l], c, 0, 0, 0);
#pragma unroll
    for (int r = 0; r < 4; ++r) {
      int m = kq + r;  // C row
      float hv = fmaxf(c[r], 0.f);
      Hs[w][m][(nt * 16 + col) ^ ((m & 7) << 3)] = (ushort)f2bfs(hv);
    }
  }
  // zero-pad j = 48..63
#pragma unroll
  for (int r = 0; r < 4; ++r) {
    int m = kq + r;
    Hs[w][m][(48 + col) ^ ((m & 7) << 3)] = 0;
  }

  // ---- read A-fragments of H (per-lane row = col) ----
  int m2 = col, X = (m2 & 7) << 3;
  ushort4 r0 = *(const ushort4*)&Hs[w][m2][(kq +  0) ^ X];
  ushort4 r1 = *(const ushort4*)&Hs[w][m2][(kq + 16) ^ X];
  ushort4 r2 = *(const ushort4*)&Hs[w][m2][(kq + 32) ^ X];
  ushort4 r3 = *(const ushort4*)&Hs[w][m2][(kq + 48) ^ X];
  short8 A20, A21;
  A20[0] = (short)r0.x; A20[1] = (short)r0.y; A20[2] = (short)r0.z; A20[3] = (short)r0.w;
  A20[4] = (short)r1.x; A20[5] = (short)r1.y; A20[6] = (short)r1.z; A20[7] = (short)r1.w;
  A21[0] = (short)r2.x; A21[1] = (short)r2.y; A21[2] = (short)r2.z; A21[3] = (short)r2.w;
  A21[4] = (short)r3.x; A21[5] = (short)r3.y; A21[6] = (short)r3.z; A21[7] = (short)r3.w;

  // ---- GEMM2 chunks fused with TP contraction ----
  float acc0[4]  = {0.f, 0.f, 0.f, 0.f};
  float accP2[4] = {0.f, 0.f, 0.f, 0.f};
  float acc1o[3][4] = {{0.f,0.f,0.f,0.f},{0.f,0.f,0.f,0.f},{0.f,0.f,0.f,0.f}};
  float acc1e[3][4] = {{0.f,0.f,0.f,0.f},{0.f,0.f,0.f,0.f},{0.f,0.f,0.f,0.f}};
  int er0 = eb + kq;           // C-row edge base (block-local)
  int iloc = col >> 2;
  int o = col & 3;

  // w00: ck 0..15, c = col, coeff = s_i*sh0*N0F, i = ck
#pragma unroll 4
  for (int ck = 0; ck < 16; ++ck) {
    float bias = b2[ck * 16 + col];
    f32x4 c = {bias, bias, bias, bias};
    c = __builtin_amdgcn_mfma_f32_16x16x32_bf16(A20, w2f[(ck * 2 + 0) * 64 + l], c, 0, 0, 0);
    c = __builtin_amdgcn_mfma_f32_16x16x32_bf16(A21, w2f[(ck * 2 + 1) * 64 + l], c, 0, 0, 0);
#pragma unroll
    for (int r = 0; r < 4; ++r)
      acc0[r] = fmaf(cSs[ck][er0 + r], c[r], acc0[r]);
  }

  // w01: ck 16..19, k=256+4i+o, i=(ck-16)*4+iloc -> accP2 (pre2)
#pragma unroll
  for (int ck = 16; ck < 20; ++ck) {
    float bias = b2[ck * 16 + col];
    f32x4 c = {bias, bias, bias, bias};
    c = __builtin_amdgcn_mfma_f32_16x16x32_bf16(A20, w2f[(ck * 2 + 0) * 64 + l], c, 0, 0, 0);
    c = __builtin_amdgcn_mfma_f32_16x16x32_bf16(A21, w2f[(ck * 2 + 1) * 64 + l], c, 0, 0, 0);
#pragma unroll
    for (int r = 0; r < 4; ++r) {
      float q = rawSs[(ck - 16) * 4 + iloc][er0 + r] * c[r];
      q += __shfl_xor(q, 4);
      q += __shfl_xor(q, 8);
      accP2[r] += q;
    }
  }

  // w10: ck 20, k=320+4i+o, coeff v_i[d]*sh0*INV3*N1OF
  {
    float bias = b2[20 * 16 + col];
    f32x4 c = {bias, bias, bias, bias};
    c = __builtin_amdgcn_mfma_f32_16x16x32_bf16(A20, w2f[(20 * 2 + 0) * 64 + l], c, 0, 0, 0);
    c = __builtin_amdgcn_mfma_f32_16x16x32_bf16(A21, w2f[(20 * 2 + 1) * 64 + l], c, 0, 0, 0);
#pragma unroll
    for (int d = 0; d < 3; ++d)
#pragma unroll
      for (int r = 0; r < 4; ++r) {
        float q = vS0s[iloc * 3 + d][er0 + r] * c[r];
        q += __shfl_xor(q, 4);
        q += __shfl_xor(q, 8);
        acc1o[d][r] += q;
      }
  }

  // w110: ck 21..24, c = col, coeff = vd_i*N0F, i = ck-21
#pragma unroll
  for (int ck = 21; ck < 25; ++ck) {
    float bias = b2[ck * 16 + col];
    f32x4 c = {bias, bias, bias, bias};
    c = __builtin_amdgcn_mfma_f32_16x16x32_bf16(A20, w2f[(ck * 2 + 0) * 64 + l], c, 0, 0, 0);
    c = __builtin_amdgcn_mfma_f32_16x16x32_bf16(A21, w2f[(ck * 2 + 1) * 64 + l], c, 0, 0, 0);
#pragma unroll
    for (int r = 0; r < 4; ++r)
      acc0[r] = fmaf(cVDs[ck - 21][er0 + r], c[r], acc0[r]);
  }

  // w111: ck 25, k=400+4i+o, coeff cr_i[d]
  {
    float bias = b2[25 * 16 + col];
    f32x4 c = {bias, bias, bias, bias};
    c = __builtin_amdgcn_mfma_f32_16x16x32_bf16(A20, w2f[(25 * 2 + 0) * 64 + l], c, 0, 0, 0);
    c = __builtin_amdgcn_mfma_f32_16x16x32_bf16(A21, w2f[(25 * 2 + 1) * 64 + l], c, 0, 0, 0);
#pragma unroll
    for (int d = 0; d < 3; ++d)
#pragma unroll
      for (int r = 0; r < 4; ++r) {
        float q = cCRs[iloc * 3 + d][er0 + r] * c[r];
        q += __shfl_xor(q, 4);
        q += __shfl_xor(q, 8);
        acc1e[d][r] += q;
      }
  }

  // ---- scatter ----
#pragma unroll
  for (int r = 0; r < 4; ++r) {
    int e = er0 + r;
    float* base = seg + ((size_t)t * NN + dsts[e]) * 40;
    atomAdd(base + col, acc0[r]);
  }
  if (col < 4) {
#pragma unroll
    for (int r = 0; r < 4; ++r) {
      int e = er0 + r;
      float* base = seg + ((size_t)t * NN + dsts[e]) * 40;
#pragma unroll
      for (int d = 0; d < 3; ++d) {
        atomAdd(base + 16 + 3 * o + d, fmaf(accP2[r], sh1fs[d][e], acc1o[d][r]));
        atomAdd(base + 28 + 3 * o + d, acc1e[d][r]);
      }
    }
  }
}

// ---------------- stats + normalize (unchanged) ----------------
__global__ __launch_bounds__(256) void k_stats(float* __restrict__ seg,
                                               const float* __restrict__ cnt,
                                               const float* __restrict__ xsc,
                                               float* __restrict__ stats) {
  int b = blockIdx.x;
  int t = b / 40;
  int chunk = b - t * 40;
  int n = chunk * 256 + threadIdx.x;
  float p[5] = {0.f, 0.f, 0.f, 0.f, 0.f};
  float q[5] = {0.f, 0.f, 0.f, 0.f, 0.f};
  if (n < NN) {
    float rc = 1.f / fmaxf(cnt[n], 1.f);
    float* sp = seg + ((size_t)t * NN + n) * 40;
    const float* xp = xsc + ((size_t)t * NN + n) * 16;
#pragma unroll
    for (int c = 0; c < 40; ++c) {
      float y = sp[c] * rc + (c < 16 ? xp[c] : 0.f);
      sp[c] = y;
      p[c % 5] += y;
      q[c % 5] = fmaf(y, y, q[c % 5]);
    }
  }
#pragma unroll
  for (int r = 0; r < 5; ++r) {
#pragma unroll
    for (int m = 32; m >= 1; m >>= 1) {
      p[r] += __shfl_xor(p[r], m);
      q[r] += __shfl_xor(q[r], m);
    }
  }
  __shared__ float ls[4][10];
  int lane = threadIdx.x & 63, wv = threadIdx.x >> 6;
  if (lane == 0) {
#pragma unroll
    for (int r = 0; r < 5; ++r) { ls[wv][r] = p[r]; ls[wv][5 + r] = q[r]; }
  }
  __syncthreads();
  if (threadIdx.x < 10) {
    int tid = threadIdx.x;
    float sum = ls[0][tid] + ls[1][tid] + ls[2][tid] + ls[3][tid];
    int r = tid % 5;
    int j = 8 * r + t;
    atomAdd(stats + (tid >= 5 ? 40 + j : j), sum);
  }
}

__global__ __launch_bounds__(256) void k_norm(const float* __restrict__ seg,
                                              const float* __restrict__ stats,
                                              const float* __restrict__ gam,
                                              const float* __restrict__ bet,
                                              float* __restrict__ out) {
  int idx = blockIdx.x * 256 + threadIdx.x;
  if (idx >= TT * NN * CC) return;
  int c = idx % 40;
  int t = idx / (NN * CC);
  int j = 8 * (c % 5) + t;
  const float inv = 1.f / (8.f * (float)NN);
  float mu = stats[j] * inv;
  float var = stats[40 + j] * inv - mu * mu;
  float y = seg[idx];
  out[idx] = (y - mu) * rsqrtf(var + EPSV) * gam[j] + bet[j];
}

extern "C" void kernel_launch(void* const* d_in, const int* in_sizes, int n_in,
                              void* d_out, int out_size, void* d_ws, size_t ws_size,
                              hipStream_t stream) {
  const float* x   = (const float*)d_in[0];
  const int*   ei  = (const int*)d_in[1];
  const float* ea  = (const float*)d_in[2];
  const float* esh = (const float*)d_in[3];
  const float* W1  = (const float*)d_in[4];
  const float* b1  = (const float*)d_in[5];
  const float* W2  = (const float*)d_in[6];
  const float* b2  = (const float*)d_in[7];
  const float* wr  = (const float*)d_in[8];
  const float* wi  = (const float*)d_in[9];
  const float* gam = (const float*)d_in[10];
  const float* bet = (const float*)d_in[11];
  float* out = (float*)d_out;

  float* ws    = (float*)d_ws;
  float* seg   = ws;                            // T*N*40 = 3,200,000 f
  float* cnt   = seg + (size_t)TT * NN * CC;    // 10,000 f
  float* stats = cnt + NN;                      // 80 f
  float* xsc   = stats + 80;                    // T*N*16 = 1,280,000 f
  short* W1F   = (short*)(xsc + (size_t)TT * NN * 16);  // 3072 bf16
  short* W2F   = W1F + 3 * 2 * 64 * 8;                  // 26624 bf16

  hipMemsetAsync(seg, 0, ((size_t)TT * NN * CC + NN + 80) * sizeof(float), stream);

  k_prep<<<(29696 + 255) / 256, 256, 0, stream>>>(W1, W2, W1F, W2F);
  k_spec<<<(NN + 255) / 256, 256, 0, stream>>>(x, wr, wi, xsc);
  k_cnt<<<EE / 256, 256, 0, stream>>>(ei, cnt);
  k_edge2<<<TT * (EE / 64), 256, 0, stream>>>(x, ei, ea, esh, W1F, W2F, b1, b2, seg);
  k_stats<<<8 * 40, 256, 0, stream>>>(seg, cnt, xsc, stats);
  k_norm<<<(TT * NN * CC + 255) / 256, 256, 0, stream>>>(seg, stats, gam, bet, out);
}